// Round 5
// baseline (1959.446 us; speedup 1.0000x reference)
//
#include <hip/hip_runtime.h>
#include <stdint.h>
#include <stddef.h>

#define L_SEQ 2048
#define NB 4
#define NH 16
#define HDIM 64
#define DMODEL 1024
// 1/sqrt(64) * log2(e): softmax computed in exp2 domain
#define ATT_SCALE_L2E 0.1803368801f

typedef __attribute__((ext_vector_type(4))) float f32x4;
typedef __attribute__((ext_vector_type(16))) float f32x16;
typedef __attribute__((ext_vector_type(8))) __bf16 bf16x8;
typedef __attribute__((ext_vector_type(4))) __bf16 bf16x4;

__device__ __forceinline__ void gload16(const void* g, void* l) {
  __builtin_amdgcn_global_load_lds((const __attribute__((address_space(1))) void*)g,
                                   (__attribute__((address_space(3))) void*)l, 16, 0, 0);
}

// ---------------- prep: x fp32 -> bf16 ----------------
__global__ void k_convert_x(const float* __restrict__ x, __bf16* __restrict__ xb) {
  int i = (blockIdx.x * 256 + threadIdx.x) * 4;
  float4 v = *(const float4*)(x + i);
  bf16x4 o;
  o[0] = (__bf16)v.x; o[1] = (__bf16)v.y; o[2] = (__bf16)v.z; o[3] = (__bf16)v.w;
  *(bf16x4*)(xb + i) = o;
}

// ---------------- prep: W (RxC fp32) -> Wt (CxR bf16) ----------------
__global__ void k_transpose_bf16(const float* __restrict__ W, __bf16* __restrict__ Wt,
                                 int R, int C) {
  __shared__ float t[32][33];
  int c0 = blockIdx.x * 32, r0 = blockIdx.y * 32;
  int tx = threadIdx.x, ty = threadIdx.y;  // 32 x 8
#pragma unroll
  for (int i = 0; i < 32; i += 8)
    t[ty + i][tx] = W[(size_t)(r0 + ty + i) * C + c0 + tx];
  __syncthreads();
#pragma unroll
  for (int i = 0; i < 32; i += 8)
    Wt[(size_t)(c0 + ty + i) * R + r0 + tx] = (__bf16)t[tx][ty + i];
}

// ---------------- m97-structure GEMM: C = A(MxK) * Bt(NxK)^T + bias ----------------
template <int EPI>
__global__ __launch_bounds__(256, 2) void k_gemm(
    const __bf16* __restrict__ A, const __bf16* __restrict__ Bt,
    const float* __restrict__ bias, float* __restrict__ Cf,
    __bf16* __restrict__ Qo, __bf16* __restrict__ Ko, __bf16* __restrict__ Vto,
    int M, int N, int K) {
  __shared__ __bf16 As[128 * 32];
  __shared__ __bf16 Bs[128 * 32];
  const int tid = threadIdx.x;
  const int wave = tid >> 6, lane = tid & 63;
  const int brow = blockIdx.y * 128, bcol = blockIdx.x * 128;
  const int wr = wave >> 1, wc = wave & 1;
  const int g = lane >> 4, c16 = lane & 15;

  f32x4 acc[4][4] = {};

  const char* Ap = (const char*)(A + (size_t)(brow + wave * 16 + (lane >> 2)) * K) + (lane & 3) * 16;
  const char* Bp = (const char*)(Bt + (size_t)(bcol + wave * 16 + (lane >> 2)) * K) + (lane & 3) * 16;
  const size_t rowskip = (size_t)64 * K * 2;
  char* AsW = (char*)As + wave * 1024;
  char* BsW = (char*)Bs + wave * 1024;

  for (int k0 = 0; k0 < K; k0 += 32) {
    gload16(Ap + (size_t)k0 * 2, AsW);
    gload16(Ap + (size_t)k0 * 2 + rowskip, AsW + 4096);
    gload16(Bp + (size_t)k0 * 2, BsW);
    gload16(Bp + (size_t)k0 * 2 + rowskip, BsW + 4096);
    __syncthreads();
    bf16x8 af[4], bfr[4];
#pragma unroll
    for (int m = 0; m < 4; ++m)
      af[m] = *(const bf16x8*)(As + (wr * 64 + m * 16 + c16) * 32 + g * 8);
#pragma unroll
    for (int n = 0; n < 4; ++n)
      bfr[n] = *(const bf16x8*)(Bs + (wc * 64 + n * 16 + c16) * 32 + g * 8);
#pragma unroll
    for (int m = 0; m < 4; ++m)
#pragma unroll
      for (int n = 0; n < 4; ++n)
        acc[m][n] = __builtin_amdgcn_mfma_f32_16x16x32_bf16(af[m], bfr[n], acc[m][n], 0, 0, 0);
    __syncthreads();
  }

#pragma unroll
  for (int m = 0; m < 4; ++m) {
#pragma unroll
    for (int n = 0; n < 4; ++n) {
      int gcol = bcol + wc * 64 + n * 16 + c16;
      float bv = bias[gcol];
#pragma unroll
      for (int r = 0; r < 4; ++r) {
        int grow = brow + wr * 64 + m * 16 + g * 4 + r;
        float v = acc[m][n][r] + bv;
        if (EPI == 0) {
          int which = gcol >> 10, hh = (gcol >> 6) & 15, d = gcol & 63;
          int b = grow >> 11, l = grow & 2047;
          size_t bh = (size_t)b * NH + hh;
          if (which == 0)
            Qo[(bh * L_SEQ + l) * HDIM + d] = (__bf16)(v * ATT_SCALE_L2E);
          else if (which == 1)
            Ko[(bh * L_SEQ + l) * HDIM + d] = (__bf16)v;
          else
            Vto[(bh * HDIM + d) * L_SEQ + l] = (__bf16)v;
        } else {
          Cf[(size_t)grow * N + gcol] = v;
        }
      }
    }
  }
}

// ---------------- helpers ----------------
__device__ __forceinline__ float fexp2(float x) {
  float r;
  asm("v_exp_f32 %0, %1" : "=v"(r) : "v"(x));
  return r;
}
__device__ __forceinline__ int cvtpk(float a, float b) {
  int r;
  asm("v_cvt_pk_bf16_f32 %0, %1, %2" : "=v"(r) : "v"(a), "v"(b));
  return r;
}
// NOTE: only safe when a and b are DISTINCT values (distinct registers).
// Aliased operands (v_permlane32_swap vX, vX) are undefined -- was the round-4 bug.
__device__ __forceinline__ void pswap(int& a, int& b) {
  asm("v_permlane32_swap_b32 %0, %1" : "+v"(a), "+v"(b));
}
// Build PV A-fragment from 8 in-lane P values (verified rounds 1-3)
__device__ __forceinline__ bf16x8 make_pa(float p0, float p1, float p2, float p3,
                                          float p4, float p5, float p6, float p7) {
  int a0 = cvtpk(p0, p1);
  int a1 = cvtpk(p2, p3);
  int b0 = cvtpk(p4, p5);
  int b1 = cvtpk(p6, p7);
  pswap(a0, b0);
  pswap(a1, b1);
  union { int i[4]; bf16x8 v; } u;
  u.i[0] = a0; u.i[1] = a1; u.i[2] = b0; u.i[3] = b1;
  return u.v;
}

// ---------------- flash attention: 2-way KV-split, 8 waves/SIMD ----------------
// Block = 256 thr = 4 waves: wave w -> q-subtile (w&1), kv-half (w>>1).
// Wave owns 32 q-rows over 1024 kv; pairs (0,2),(1,3) merge via LDS at the end.
__global__ __launch_bounds__(256, 8) void k_attn(
    const __bf16* __restrict__ Q, const __bf16* __restrict__ K,
    const __bf16* __restrict__ Vt, __bf16* __restrict__ O) {
  __shared__ float smO0[2][64][17];
  __shared__ float smO1[2][64][17];
  __shared__ float smM[2][64];
  __shared__ float smL[2][64];

  // XCD-aware decode over 2048 blocks: 8 heads per XCD -> K/V L2-resident
  const int blk = blockIdx.x;
  const int idx = (blk & 7) * 256 + (blk >> 3);  // bijective
  const int bh = idx >> 5;
  const int qg = idx & 31;                       // 32 groups of 64 q-rows
  const int wave = threadIdx.x >> 6, lane = threadIdx.x & 63;
  const int qsub = wave & 1, kvhalf = wave >> 1;
  const int r31 = lane & 31, hi = lane >> 5;
  const int qw = qg * 64 + qsub * 32;
  const int k0 = kvhalf * 1024, k1 = k0 + 1024;
  const __bf16* Qb = Q + (size_t)bh * L_SEQ * HDIM;
  const __bf16* Kb = K + (size_t)bh * L_SEQ * HDIM;
  const __bf16* Vb = Vt + (size_t)bh * HDIM * L_SEQ;

  // Q fragments (B-operand): q = lane&31, hdim slice kc*16 + hi*8 + {0..7}
  bf16x8 qf[4];
#pragma unroll
  for (int kc = 0; kc < 4; ++kc)
    qf[kc] = *(const bf16x8*)(Qb + (size_t)(qw + r31) * HDIM + kc * 16 + hi * 8);

  f32x16 o0 = {}, o1 = {};  // O accum: rows q reg-mapped, col d = lane&31 (+32)
  float m = -1e30f, l = 0.f;  // per-lane: row q = lane&31; l covers own kv half-rows

#define LOADK(dst, kvb) do {                                          \
    const __bf16* kp_ = Kb + (size_t)((kvb) + r31) * HDIM + hi * 8;   \
    dst[0] = *(const bf16x8*)(kp_);                                   \
    dst[1] = *(const bf16x8*)(kp_ + 16);                              \
    dst[2] = *(const bf16x8*)(kp_ + 32);                              \
    dst[3] = *(const bf16x8*)(kp_ + 48);                              \
  } while (0)

#define LOADV(dst, kvb) do {                                          \
    const __bf16* vp_ = Vb + (size_t)r31 * L_SEQ + (kvb) + hi * 8;    \
    dst[0][0] = *(const bf16x8*)(vp_);                                \
    dst[1][0] = *(const bf16x8*)(vp_ + 16);                           \
    dst[0][1] = *(const bf16x8*)(vp_ + 32 * L_SEQ);                   \
    dst[1][1] = *(const bf16x8*)(vp_ + 32 * L_SEQ + 16);              \
  } while (0)

#define BODY(kf, vf) do {                                                          \
    f32x16 s = {};                                                                 \
    _Pragma("unroll")                                                              \
    for (int kc = 0; kc < 4; ++kc)                                                 \
      s = __builtin_amdgcn_mfma_f32_32x32x16_bf16(kf[kc], qf[kc], s, 0, 0, 0);     \
    float t8[8];                                                                   \
    _Pragma("unroll") for (int i = 0; i < 8; ++i) t8[i] = fmaxf(s[i], s[i + 8]);   \
    _Pragma("unroll") for (int i = 0; i < 4; ++i) t8[i] = fmaxf(t8[i], t8[i + 4]); \
    float mx = fmaxf(fmaxf(t8[0], t8[1]), fmaxf(t8[2], t8[3]));                    \
    mx = fmaxf(mx, __shfl_xor(mx, 32, 64));                                        \
    if (__any(mx > m + 12.f)) {                                                    \
      float mnew = fmaxf(m, mx);                                                   \
      float corr = fexp2(m - mnew);                                                \
      l *= corr;                                                                   \
      _Pragma("unroll") for (int r = 0; r < 16; ++r) {                             \
        float cr = __shfl(corr, (r & 3) + 8 * (r >> 2) + 4 * hi, 64);              \
        o0[r] *= cr; o1[r] *= cr;                                                  \
      }                                                                            \
      m = mnew;                                                                    \
    }                                                                              \
    _Pragma("unroll") for (int i = 0; i < 16; ++i) s[i] = fexp2(s[i] - m);         \
    float a8[8];                                                                   \
    _Pragma("unroll") for (int i = 0; i < 8; ++i) a8[i] = s[i] + s[i + 8];         \
    _Pragma("unroll") for (int i = 0; i < 4; ++i) a8[i] += a8[i + 4];              \
    l += (a8[0] + a8[1]) + (a8[2] + a8[3]);                                        \
    bf16x8 pa = make_pa(s[0], s[1], s[2], s[3], s[4], s[5], s[6], s[7]);           \
    o0 = __builtin_amdgcn_mfma_f32_32x32x16_bf16(pa, vf[0][0], o0, 0, 0, 0);       \
    o1 = __builtin_amdgcn_mfma_f32_32x32x16_bf16(pa, vf[0][1], o1, 0, 0, 0);       \
    pa = make_pa(s[8], s[9], s[10], s[11], s[12], s[13], s[14], s[15]);            \
    o0 = __builtin_amdgcn_mfma_f32_32x32x16_bf16(pa, vf[1][0], o0, 0, 0, 0);       \
    o1 = __builtin_amdgcn_mfma_f32_32x32x16_bf16(pa, vf[1][1], o1, 0, 0, 0);       \
  } while (0)

  bf16x8 kA[4], kB[4], vA[2][2], vB[2][2];
  LOADK(kA, k0);
  for (int kv0 = k0; kv0 < k1; kv0 += 64) {
    LOADV(vA, kv0);
    LOADK(kB, kv0 + 32);
    BODY(kA, vA);
    LOADV(vB, kv0 + 32);
    int nx = (kv0 + 64 > k1 - 32) ? (k1 - 32) : (kv0 + 64);
    LOADK(kA, nx);
    BODY(kB, vB);
  }
#undef LOADK
#undef LOADV
#undef BODY

  // ---- intra-wave l merge (lane halves cover disjoint kv rows) ----
  l += __shfl_xor(l, 32, 64);

  // ---- cross-wave (kv-half) merge via LDS; waves 2,3 publish ----
  if (wave >= 2) {
    int w = wave - 2;
    smM[w][lane] = m;
    smL[w][lane] = l;
#pragma unroll
    for (int r = 0; r < 16; ++r) {
      smO0[w][lane][r] = o0[r];
      smO1[w][lane][r] = o1[r];
    }
  }
  __syncthreads();
  if (wave < 2) {
    float m2 = smM[wave][lane], l2 = smL[wave][lane];
    float mt = fmaxf(m, m2);
    float c1 = fexp2(m - mt), c2 = fexp2(m2 - mt);
    float lt = l * c1 + l2 * c2;
    float linv = 1.f / lt;
    float u1 = c1 * linv, u2 = c2 * linv;
    const int b = bh >> 4, h = bh & 15;
#pragma unroll
    for (int r = 0; r < 16; ++r) {
      int ql = (r & 3) + 8 * (r >> 2) + 4 * hi;
      float s1 = __shfl(u1, ql, 64);
      float s2 = __shfl(u2, ql, 64);
      float w0 = o0[r] * s1 + smO0[wave][lane][r] * s2;
      float w1 = o1[r] * s1 + smO1[wave][lane][r] * s2;
      size_t base = ((size_t)b * L_SEQ + qw + ql) * DMODEL + h * 64 + r31;
      O[base] = (__bf16)w0;
      O[base + 32] = (__bf16)w1;
    }
  }
}

extern "C" void kernel_launch(void* const* d_in, const int* in_sizes, int n_in,
                              void* d_out, int out_size, void* d_ws, size_t ws_size,
                              hipStream_t stream) {
  const float* x = (const float*)d_in[0];
  const float* Wqkv = (const float*)d_in[1];
  const float* bqkv = (const float*)d_in[2];
  const float* Wout = (const float*)d_in[3];
  const float* bout = (const float*)d_in[4];
  float* out = (float*)d_out;

  char* ws = (char*)d_ws;
  __bf16* Xb    = (__bf16*)(ws + 0);
  __bf16* Wqkvt = (__bf16*)(ws + 16777216);
  __bf16* Woutt = (__bf16*)(ws + 23068672);
  __bf16* Qb    = (__bf16*)(ws + 25165824);
  __bf16* Kb    = (__bf16*)(ws + 41943040);
  __bf16* Vtb   = (__bf16*)(ws + 58720256);
  __bf16* Ob    = (__bf16*)(ws + 0);  // reuse Xb region after GEMM1

  k_convert_x<<<8192, 256, 0, stream>>>(x, Xb);
  k_transpose_bf16<<<dim3(96, 32), dim3(32, 8), 0, stream>>>(Wqkv, Wqkvt, 1024, 3072);
  k_transpose_bf16<<<dim3(32, 32), dim3(32, 8), 0, stream>>>(Wout, Woutt, 1024, 1024);
  k_gemm<0><<<dim3(24, 64), 256, 0, stream>>>(Xb, Wqkvt, bqkv, nullptr, Qb, Kb, Vtb,
                                              8192, 3072, 1024);
  k_attn<<<dim3(2048), 256, 0, stream>>>(Qb, Kb, Vtb, Ob);
  k_gemm<1><<<dim3(8, 64), 256, 0, stream>>>(Ob, Woutt, bout, out, nullptr, nullptr, nullptr,
                                             8192, 1024, 1024);
}

// Round 6
// 227.235 us; speedup vs baseline: 8.6230x; 8.6230x over previous
//
#include <hip/hip_runtime.h>
#include <stdint.h>
#include <stddef.h>

#define L_SEQ 2048
#define NB 4
#define NH 16
#define HDIM 64
#define DMODEL 1024
// 1/sqrt(64) * log2(e): softmax computed in exp2 domain
#define ATT_SCALE_L2E 0.1803368801f

typedef __attribute__((ext_vector_type(4))) float f32x4;
typedef __attribute__((ext_vector_type(16))) float f32x16;
typedef __attribute__((ext_vector_type(8))) __bf16 bf16x8;
typedef __attribute__((ext_vector_type(4))) __bf16 bf16x4;

__device__ __forceinline__ void gload16(const void* g, void* l) {
  __builtin_amdgcn_global_load_lds((const __attribute__((address_space(1))) void*)g,
                                   (__attribute__((address_space(3))) void*)l, 16, 0, 0);
}

// ---------------- prep: x fp32 -> bf16 ----------------
__global__ void k_convert_x(const float* __restrict__ x, __bf16* __restrict__ xb) {
  int i = (blockIdx.x * 256 + threadIdx.x) * 4;
  float4 v = *(const float4*)(x + i);
  bf16x4 o;
  o[0] = (__bf16)v.x; o[1] = (__bf16)v.y; o[2] = (__bf16)v.z; o[3] = (__bf16)v.w;
  *(bf16x4*)(xb + i) = o;
}

// ---------------- prep: W (RxC fp32) -> Wt (CxR bf16) ----------------
__global__ void k_transpose_bf16(const float* __restrict__ W, __bf16* __restrict__ Wt,
                                 int R, int C) {
  __shared__ float t[32][33];
  int c0 = blockIdx.x * 32, r0 = blockIdx.y * 32;
  int tx = threadIdx.x, ty = threadIdx.y;  // 32 x 8
#pragma unroll
  for (int i = 0; i < 32; i += 8)
    t[ty + i][tx] = W[(size_t)(r0 + ty + i) * C + c0 + tx];
  __syncthreads();
#pragma unroll
  for (int i = 0; i < 32; i += 8)
    Wt[(size_t)(c0 + ty + i) * R + r0 + tx] = (__bf16)t[tx][ty + i];
}

// ---------------- m97-structure GEMM: C = A(MxK) * Bt(NxK)^T + bias ----------------
template <int EPI>
__global__ __launch_bounds__(256, 2) void k_gemm(
    const __bf16* __restrict__ A, const __bf16* __restrict__ Bt,
    const float* __restrict__ bias, float* __restrict__ Cf,
    __bf16* __restrict__ Qo, __bf16* __restrict__ Ko, __bf16* __restrict__ Vto,
    int M, int N, int K) {
  __shared__ __bf16 As[128 * 32];
  __shared__ __bf16 Bs[128 * 32];
  const int tid = threadIdx.x;
  const int wave = tid >> 6, lane = tid & 63;
  const int brow = blockIdx.y * 128, bcol = blockIdx.x * 128;
  const int wr = wave >> 1, wc = wave & 1;
  const int g = lane >> 4, c16 = lane & 15;

  f32x4 acc[4][4] = {};

  const char* Ap = (const char*)(A + (size_t)(brow + wave * 16 + (lane >> 2)) * K) + (lane & 3) * 16;
  const char* Bp = (const char*)(Bt + (size_t)(bcol + wave * 16 + (lane >> 2)) * K) + (lane & 3) * 16;
  const size_t rowskip = (size_t)64 * K * 2;
  char* AsW = (char*)As + wave * 1024;
  char* BsW = (char*)Bs + wave * 1024;

  for (int k0 = 0; k0 < K; k0 += 32) {
    gload16(Ap + (size_t)k0 * 2, AsW);
    gload16(Ap + (size_t)k0 * 2 + rowskip, AsW + 4096);
    gload16(Bp + (size_t)k0 * 2, BsW);
    gload16(Bp + (size_t)k0 * 2 + rowskip, BsW + 4096);
    __syncthreads();
    bf16x8 af[4], bfr[4];
#pragma unroll
    for (int m = 0; m < 4; ++m)
      af[m] = *(const bf16x8*)(As + (wr * 64 + m * 16 + c16) * 32 + g * 8);
#pragma unroll
    for (int n = 0; n < 4; ++n)
      bfr[n] = *(const bf16x8*)(Bs + (wc * 64 + n * 16 + c16) * 32 + g * 8);
#pragma unroll
    for (int m = 0; m < 4; ++m)
#pragma unroll
      for (int n = 0; n < 4; ++n)
        acc[m][n] = __builtin_amdgcn_mfma_f32_16x16x32_bf16(af[m], bfr[n], acc[m][n], 0, 0, 0);
    __syncthreads();
  }

#pragma unroll
  for (int m = 0; m < 4; ++m) {
#pragma unroll
    for (int n = 0; n < 4; ++n) {
      int gcol = bcol + wc * 64 + n * 16 + c16;
      float bv = bias[gcol];
#pragma unroll
      for (int r = 0; r < 4; ++r) {
        int grow = brow + wr * 64 + m * 16 + g * 4 + r;
        float v = acc[m][n][r] + bv;
        if (EPI == 0) {
          int which = gcol >> 10, hh = (gcol >> 6) & 15, d = gcol & 63;
          int b = grow >> 11, l = grow & 2047;
          size_t bh = (size_t)b * NH + hh;
          if (which == 0)
            Qo[(bh * L_SEQ + l) * HDIM + d] = (__bf16)(v * ATT_SCALE_L2E);
          else if (which == 1)
            Ko[(bh * L_SEQ + l) * HDIM + d] = (__bf16)v;
          else
            Vto[(bh * HDIM + d) * L_SEQ + l] = (__bf16)v;
        } else {
          Cf[(size_t)grow * N + gcol] = v;
        }
      }
    }
  }
}

// ---------------- helpers ----------------
__device__ __forceinline__ float fexp2(float x) {
  float r;
  asm("v_exp_f32 %0, %1" : "=v"(r) : "v"(x));
  return r;
}
__device__ __forceinline__ int cvtpk(float a, float b) {
  int r;
  asm("v_cvt_pk_bf16_f32 %0, %1, %2" : "=v"(r) : "v"(a), "v"(b));
  return r;
}
// only safe when a,b are DISTINCT values (distinct registers) — round-4 lesson
__device__ __forceinline__ void pswap(int& a, int& b) {
  asm("v_permlane32_swap_b32 %0, %1" : "+v"(a), "+v"(b));
}
// Build PV A-fragment from 8 in-lane P values (verified rounds 1-3)
__device__ __forceinline__ bf16x8 make_pa(float p0, float p1, float p2, float p3,
                                          float p4, float p5, float p6, float p7) {
  int a0 = cvtpk(p0, p1);
  int a1 = cvtpk(p2, p3);
  int b0 = cvtpk(p4, p5);
  int b1 = cvtpk(p6, p7);
  pswap(a0, b0);
  pswap(a1, b1);
  union { int i[4]; bf16x8 v; } u;
  u.i[0] = a0; u.i[1] = a1; u.i[2] = b0; u.i[3] = b1;
  return u.v;
}

// ---------------- flash attention: LDS-staged KV, 2-phase pipeline ----------------
// Block = 4 waves sharing one (b,h) + 128 q-rows (wave w -> rows qt*128+w*32..+31).
// KVBLK=64 double-buffered in LDS (K 8KB + V 8KB per buf, 32 KB total), staged
// via global_load_lds (linear dest) from XOR-pre-swizzled global sources; ds_reads
// apply the same XOR (involution) -> bank-conflict-reduced. T3-lite schedule:
// STAGE(next) -> compute(cur) -> syncthreads -> flip.
__global__ __launch_bounds__(256, 4) void k_attn(
    const __bf16* __restrict__ Q, const __bf16* __restrict__ K,
    const __bf16* __restrict__ Vt, __bf16* __restrict__ O) {
  __shared__ char kv_lds[32768];

  // XCD-aware decode: 16 q-tiles of a head on one XCD -> K/V L2-resident
  const int blk = blockIdx.x;                    // 0..1023
  const int idx = (blk & 7) * 128 + (blk >> 3);  // bijective
  const int bh = idx >> 4;
  const int qt = idx & 15;
  const int tid = threadIdx.x;
  const int wave = tid >> 6, lane = tid & 63;
  const int r31 = lane & 31, hi = lane >> 5;
  const int swz = (r31 & 7) << 4;
  const int qw = qt * 128 + wave * 32;
  const __bf16* Qb = Q + (size_t)bh * L_SEQ * HDIM;
  const char* Kc = (const char*)(K + (size_t)bh * L_SEQ * HDIM);
  const char* Vc = (const char*)(Vt + (size_t)bh * HDIM * L_SEQ);

  // staging sources: pre-swizzled per-thread global addresses (rule-21: linear
  // LDS dest + inverse-swz source + swz read). Issue i covers LDS Y=i*4096+tid*16.
  const char* gK0; const char* gK1; const char* gV0; const char* gV1;
  {
    int Y0 = tid * 16, Y1 = 4096 + tid * 16;
    int r0 = Y0 >> 7, r1 = Y1 >> 7;
    int c0 = (Y0 & 127) ^ ((r0 & 7) << 4);
    int c1 = (Y1 & 127) ^ ((r1 & 7) << 4);
    gK0 = Kc + r0 * 128 + c0;
    gK1 = Kc + r1 * 128 + c1;
    gV0 = Vc + (size_t)r0 * 4096 + c0;  // r = d-row for V
    gV1 = Vc + (size_t)r1 * 4096 + c1;
  }

  // Q fragments (B-operand): q = lane&31, hdim elems kc*16 + hi*8 + {0..7}
  bf16x8 qf[4];
#pragma unroll
  for (int kc = 0; kc < 4; ++kc)
    qf[kc] = *(const bf16x8*)(Qb + (size_t)(qw + r31) * HDIM + kc * 16 + hi * 8);

  f32x16 o0 = {}, o1 = {};   // O accum: rows q reg-mapped, col d = lane&31 (+32)
  float m = -1e30f, l = 0.f; // per-lane row state (row q = lane&31)

#define STAGE(buf, kvb) do {                                                     \
    char* lb_ = kv_lds + (buf) * 16384 + wave * 1024;                            \
    gload16(gK0 + (size_t)(kvb) * 128, lb_);                                     \
    gload16(gK1 + (size_t)(kvb) * 128, lb_ + 4096);                              \
    gload16(gV0 + (kvb) * 2, lb_ + 8192);                                        \
    gload16(gV1 + (kvb) * 2, lb_ + 8192 + 4096);                                 \
  } while (0)

#define BODYL(t, bufo) do {                                                        \
    const char* kb_ = kv_lds + (bufo) + ((t) * 32 + r31) * 128;                    \
    bf16x8 kf0 = *(const bf16x8*)(kb_ + ((hi * 16) ^ swz));                        \
    bf16x8 kf1 = *(const bf16x8*)(kb_ + ((32 + hi * 16) ^ swz));                   \
    bf16x8 kf2 = *(const bf16x8*)(kb_ + ((64 + hi * 16) ^ swz));                   \
    bf16x8 kf3 = *(const bf16x8*)(kb_ + ((96 + hi * 16) ^ swz));                   \
    f32x16 s = {};                                                                 \
    s = __builtin_amdgcn_mfma_f32_32x32x16_bf16(kf0, qf[0], s, 0, 0, 0);           \
    s = __builtin_amdgcn_mfma_f32_32x32x16_bf16(kf1, qf[1], s, 0, 0, 0);           \
    s = __builtin_amdgcn_mfma_f32_32x32x16_bf16(kf2, qf[2], s, 0, 0, 0);           \
    s = __builtin_amdgcn_mfma_f32_32x32x16_bf16(kf3, qf[3], s, 0, 0, 0);           \
    float t8[8];                                                                   \
    _Pragma("unroll") for (int i = 0; i < 8; ++i) t8[i] = fmaxf(s[i], s[i + 8]);   \
    _Pragma("unroll") for (int i = 0; i < 4; ++i) t8[i] = fmaxf(t8[i], t8[i + 4]); \
    float mx = fmaxf(fmaxf(t8[0], t8[1]), fmaxf(t8[2], t8[3]));                    \
    mx = fmaxf(mx, __shfl_xor(mx, 32, 64));                                        \
    if (__any(mx > m + 12.f)) {                                                    \
      float mnew = fmaxf(m, mx);                                                   \
      float corr = fexp2(m - mnew);                                                \
      l *= corr;                                                                   \
      _Pragma("unroll") for (int r = 0; r < 16; ++r) {                             \
        float cr = __shfl(corr, (r & 3) + 8 * (r >> 2) + 4 * hi, 64);              \
        o0[r] *= cr; o1[r] *= cr;                                                  \
      }                                                                            \
      m = mnew;                                                                    \
    }                                                                              \
    _Pragma("unroll") for (int i = 0; i < 16; ++i) s[i] = fexp2(s[i] - m);         \
    float a8[8];                                                                   \
    _Pragma("unroll") for (int i = 0; i < 8; ++i) a8[i] = s[i] + s[i + 8];         \
    _Pragma("unroll") for (int i = 0; i < 4; ++i) a8[i] += a8[i + 4];              \
    l += (a8[0] + a8[1]) + (a8[2] + a8[3]);                                        \
    const char* vb_ = kv_lds + (bufo) + 8192 + r31 * 128;                          \
    bf16x8 pa = make_pa(s[0], s[1], s[2], s[3], s[4], s[5], s[6], s[7]);           \
    o0 = __builtin_amdgcn_mfma_f32_32x32x16_bf16(                                  \
        pa, *(const bf16x8*)(vb_ + (((t) * 64 + hi * 16) ^ swz)), o0, 0, 0, 0);    \
    o1 = __builtin_amdgcn_mfma_f32_32x32x16_bf16(                                  \
        pa, *(const bf16x8*)(vb_ + 4096 + (((t) * 64 + hi * 16) ^ swz)), o1, 0, 0, 0); \
    pa = make_pa(s[8], s[9], s[10], s[11], s[12], s[13], s[14], s[15]);            \
    o0 = __builtin_amdgcn_mfma_f32_32x32x16_bf16(                                  \
        pa, *(const bf16x8*)(vb_ + (((t) * 64 + 32 + hi * 16) ^ swz)), o0, 0, 0, 0); \
    o1 = __builtin_amdgcn_mfma_f32_32x32x16_bf16(                                  \
        pa, *(const bf16x8*)(vb_ + 4096 + (((t) * 64 + 32 + hi * 16) ^ swz)), o1, 0, 0, 0); \
  } while (0)

  int cur = 0;
  STAGE(0, 0);
  __syncthreads();
  for (int t = 0; t < L_SEQ / 64; ++t) {
    if (t < L_SEQ / 64 - 1) STAGE(cur ^ 1, (t + 1) * 64);
    BODYL(0, cur * 16384);
    BODYL(1, cur * 16384);
    __syncthreads();  // drains vmcnt (stage) + lgkm, then barrier: next buf ready
    cur ^= 1;
  }
#undef STAGE
#undef BODYL

  // ---- merge lane halves of l (disjoint kv rows) and store ----
  l += __shfl_xor(l, 32, 64);
  const int b = bh >> 4, h = bh & 15;
  float linv = 1.f / l;
#pragma unroll
  for (int r = 0; r < 16; ++r) {
    int ql = (r & 3) + 8 * (r >> 2) + 4 * hi;
    float li = __shfl(linv, ql, 64);
    size_t base = ((size_t)b * L_SEQ + qw + ql) * DMODEL + h * 64 + r31;
    O[base] = (__bf16)(o0[r] * li);
    O[base + 32] = (__bf16)(o1[r] * li);
  }
}

extern "C" void kernel_launch(void* const* d_in, const int* in_sizes, int n_in,
                              void* d_out, int out_size, void* d_ws, size_t ws_size,
                              hipStream_t stream) {
  const float* x = (const float*)d_in[0];
  const float* Wqkv = (const float*)d_in[1];
  const float* bqkv = (const float*)d_in[2];
  const float* Wout = (const float*)d_in[3];
  const float* bout = (const float*)d_in[4];
  float* out = (float*)d_out;

  char* ws = (char*)d_ws;
  __bf16* Xb    = (__bf16*)(ws + 0);
  __bf16* Wqkvt = (__bf16*)(ws + 16777216);
  __bf16* Woutt = (__bf16*)(ws + 23068672);
  __bf16* Qb    = (__bf16*)(ws + 25165824);
  __bf16* Kb    = (__bf16*)(ws + 41943040);
  __bf16* Vtb   = (__bf16*)(ws + 58720256);
  __bf16* Ob    = (__bf16*)(ws + 0);  // reuse Xb region after GEMM1

  k_convert_x<<<8192, 256, 0, stream>>>(x, Xb);
  k_transpose_bf16<<<dim3(96, 32), dim3(32, 8), 0, stream>>>(Wqkv, Wqkvt, 1024, 3072);
  k_transpose_bf16<<<dim3(32, 32), dim3(32, 8), 0, stream>>>(Wout, Woutt, 1024, 1024);
  k_gemm<0><<<dim3(24, 64), 256, 0, stream>>>(Xb, Wqkvt, bqkv, nullptr, Qb, Kb, Vtb,
                                              8192, 3072, 1024);
  k_attn<<<dim3(1024), 256, 0, stream>>>(Qb, Kb, Vtb, Ob);
  k_gemm<1><<<dim3(8, 64), 256, 0, stream>>>(Ob, Woutt, bout, out, nullptr, nullptr, nullptr,
                                             8192, 1024, 1024);
}